// Round 8
// baseline (178.613 us; speedup 1.0000x reference)
//
#include <hip/hip_runtime.h>

// DownSampler fused: x[16,3,512,512] -> out[16,3,128,128] (C folded into N: 48 imgs)
//  S1: reflect-pad1 + 4x4/s2 conv (1->20) + relu   (MFMA 32x32x16 f16, taps from global)
//  S2: reflect-pad1 + 4x4/s2 conv (20->20) + relu  (MFMA 32x32x16 f16)
//  S3: 3x3 zero-pad1 conv (20->1) + relu           (VALU dot2 f16)
//
// Round 8: stage A also on the matrix pipe. TS=12 => o1pad tile 30x30; per
// half (7 o2 rows) stage A = 16 one-row chunks of 32 cols, one mfma each
// (M=32 positions, N=20 channels, K=16 taps). All activations f16 (pkrtz
// 1-op pack). Invalid/pad slots may hold garbage; every consumer masks them
// (proof: o1pad rows/cols outside [0,258) only feed o2 halo positions, which
// the epilogue zeroes). 4 barriers. LDS 39,840 B -> 4 blocks/CU.

#define NC 20
#define TS 12     // output tile
#define OT 14     // o2 tile (TS+2)
#define AR 16     // o1pad rows per half
#define SO1 48    // s_o1 row stride (shorts); 2*SO1 = 48 dw ≡ 16 mod 32 -> kh halves on disjoint banks
#define PS1 770   // s_o1 channel plane stride (shorts) = 16*48+2 (385 dw, odd -> scatter conflict-free)
#define SO2 16    // s_o2 row stride (shorts)
#define PS2 226   // s_o2 channel plane stride (shorts) = 14*16+2

// d_ws layout (u32):
//   [0,256)       w1f[lane][4]   f16 MFMA B-frags: B[k=(l>>5)*8+j][ch=l&31] = w1[ch][k]
//   [256,5376)    w2f[cin][lane][4]  f16 B-frags: B[k][cout] = w2[cout][cin][k]
//   [5376,5556)   w3p[c][di][which]  f16 pairs; 0=(w0,w1) 1=(w2,0) 2=(0,w2)
#define W2F_OFF 256
#define W3_OFF  5376
#define WP_N    5556

typedef _Float16 h2  __attribute__((ext_vector_type(2)));
typedef __fp16   hq2 __attribute__((ext_vector_type(2)));   // cvt_pkrtz ret type
typedef _Float16 h8  __attribute__((ext_vector_type(8)));
typedef float    f32x16 __attribute__((ext_vector_type(16)));

__device__ __forceinline__ float dot2(unsigned int a, unsigned int b, float c) {
    return __builtin_amdgcn_fdot2(__builtin_bit_cast(h2, a),
                                  __builtin_bit_cast(h2, b), c, false);
}
__device__ __forceinline__ unsigned int packh(float a, float b) {
    _Float16 ha = (_Float16)a, hb = (_Float16)b;
    return (unsigned int)__builtin_bit_cast(unsigned short, ha) |
           ((unsigned int)__builtin_bit_cast(unsigned short, hb) << 16);
}
__device__ __forceinline__ unsigned int pkrtz(float a, float b) {
    hq2 r = __builtin_amdgcn_cvt_pkrtz(a, b);
    return __builtin_bit_cast(unsigned int, r);
}
__device__ __forceinline__ unsigned short f2h(float a) {
    _Float16 h = (_Float16)a;
    return __builtin_bit_cast(unsigned short, h);
}
__device__ __forceinline__ int refl256(int q) {          // reflect into [0,256)
    q = (q < 0) ? -q : q; return (q > 255) ? 510 - q : q;
}
__device__ __forceinline__ int refl512(int q) {          // reflect into [0,512)
    q = (q < 0) ? -q : q; return (q > 511) ? 1022 - q : q;
}

__global__ __launch_bounds__(256) void pack_weights(
    const float* __restrict__ w1, const float* __restrict__ w2,
    const float* __restrict__ w3, unsigned int* __restrict__ wp)
{
    const int i = blockIdx.x * 256 + threadIdx.x;
    if (i >= WP_N) return;
    if (i < W2F_OFF) {                      // w1f
        const int lane = i >> 2, jp = i & 3;
        const int ch = lane & 31, k0 = (lane >> 5) * 8 + 2 * jp;
        wp[i] = (ch < NC) ? packh(w1[ch * 16 + k0], w1[ch * 16 + k0 + 1]) : 0u;
    } else if (i < W3_OFF) {                // w2f
        const int t = i - W2F_OFF;
        const int cin = t >> 8, r = t & 255;
        const int lane = r >> 2, jp = r & 3;
        const int cout = lane & 31, k0 = (lane >> 5) * 8 + 2 * jp;
        wp[i] = (cout < NC) ? packh(w2[(cout * NC + cin) * 16 + k0],
                                    w2[(cout * NC + cin) * 16 + k0 + 1]) : 0u;
    } else {                                // w3p
        const int t = i - W3_OFF;
        const int c = t / 9;
        const int r = t - c * 9;
        const int di = r / 3, wh = r - di * 3;
        const float* row = w3 + c * 9 + di * 3;
        float a, b;
        if (wh == 0)      { a = row[0]; b = row[1]; }
        else if (wh == 1) { a = row[2]; b = 0.f;    }
        else              { a = 0.f;    b = row[2]; }
        wp[i] = packh(a, b);
    }
}

__global__ __launch_bounds__(256, 4) void ds_fused(
    const float* __restrict__ x,              // [48][512][512]
    const unsigned int* __restrict__ wp,      // packed weights (d_ws)
    float* __restrict__ out)                  // [48][128][128]
{
    __shared__ __attribute__((aligned(16))) unsigned short s_o1[NC * PS1]; // 30,800 B
    __shared__ __attribute__((aligned(16))) unsigned short s_o2[NC * PS2]; //  9,040 B

    const int bid  = blockIdx.x;
    const int img  = bid / 121;
    const int t121 = bid - img * 121;
    const int ty   = t121 / 11;
    const int tx   = t121 - ty * 11;
    const int y0   = ty * TS;
    const int x0   = tx * TS;
    const int tid  = threadIdx.x;
    const int lane = tid & 63;
    const int wv   = tid >> 6;
    const int l31  = lane & 31;
    const int kh   = lane >> 5;

    const float* __restrict__ xi = x + (size_t)img * (512 * 512);
    const uint4* __restrict__ w1f = (const uint4*)wp;
    const uint4* __restrict__ w2f = (const uint4*)(wp + W2F_OFF);
    const unsigned int* __restrict__ w3p = wp + W3_OFF;

    const int t0 = 2 * y0 - 2;            // o1pad row base of tile
    const int s0 = 2 * x0 - 2;            // o1pad col base

    // ---- stage-A per-lane column data (chunk covers cols b = l31) ----
    const int sA = s0 + l31;              // o1pad col (may overflow: garbage-safe)
    const bool edgeT = (tx == 0) || (tx == 10);   // only tiles where col reflect can wrap
    const int vb = 2 * sA - 3;            // fast path: taps vb..vb+3 (interior-proven)
    int v0 = 0, v1 = 0, v2 = 0, v3 = 0;
    if (edgeT) {
        const int n2 = refl256(sA - 1);
        const int vbb = 2 * n2 - 1;
        v0 = refl512(vbb);     v1 = refl512(vbb + 1);
        v2 = refl512(vbb + 2); v3 = refl512(vbb + 3);
    }
    const h8 w1frag = __builtin_bit_cast(h8, w1f[lane]);

    // ---- stage-B per-lane position (chunk = wv), h-independent ----
    const int q  = 32 * wv + l31;         // 0..127; valid < 98 (7x14 per half)
    const int qc = (q < 98) ? q : 0;      // clamp invalid lanes to a safe addr
    const int li = (qc * 2341) >> 15;     // /14 for q<128
    const int jl = qc - li * 14;
    const int offA = (2 * li + 2 * kh) * SO1 + 2 * jl;   // shorts, within plane

    #pragma unroll
    for (int h = 0; h < 2; ++h) {
        // ---- stage A: 16 one-row chunks -> s_o1 (f16) ----
        for (int c = wv; c < AR; c += 4) {
            const int t = t0 + 14 * h + c;          // o1pad row (garbage-safe OOR)
            const int mrow = refl256(t - 1);
            const int rb = 2 * mrow - 1;
            const float* r0 = xi + refl512(rb)     * 512;
            const float* r1 = xi + refl512(rb + 1) * 512;
            const float* r2 = xi + refl512(rb + 2) * 512;
            const float* r3 = xi + refl512(rb + 3) * 512;
            const float* plo = kh ? r2 : r0;
            const float* phi = kh ? r3 : r1;
            float f0, f1, f2, f3, f4, f5, f6, f7;
            if (!edgeT) {
                const float* a0 = plo + vb;
                f0 = a0[0]; f1 = a0[1]; f2 = a0[2]; f3 = a0[3];
                const float* a1 = phi + vb;
                f4 = a1[0]; f5 = a1[1]; f6 = a1[2]; f7 = a1[3];
            } else {
                f0 = plo[v0]; f1 = plo[v1]; f2 = plo[v2]; f3 = plo[v3];
                f4 = phi[v0]; f5 = phi[v1]; f6 = phi[v2]; f7 = phi[v3];
            }
            uint4 aw;
            aw.x = pkrtz(f0, f1); aw.y = pkrtz(f2, f3);
            aw.z = pkrtz(f4, f5); aw.w = pkrtz(f6, f7);
            f32x16 o = {};
            o = __builtin_amdgcn_mfma_f32_32x32x16_f16(
                    __builtin_bit_cast(h8, aw), w1frag, o, 0, 0, 0);
            // C-layout: n=ch=l31, m=col b=(reg&3)+8*(reg>>2)+4*kh
            if (l31 < NC) {
                unsigned int* wr =
                    (unsigned int*)&s_o1[l31 * PS1 + c * SO1 + 4 * kh];
                wr[0]  = pkrtz(fmaxf(o[0],  0.f), fmaxf(o[1],  0.f));
                wr[1]  = pkrtz(fmaxf(o[2],  0.f), fmaxf(o[3],  0.f));
                wr[4]  = pkrtz(fmaxf(o[4],  0.f), fmaxf(o[5],  0.f));
                wr[5]  = pkrtz(fmaxf(o[6],  0.f), fmaxf(o[7],  0.f));
                wr[8]  = pkrtz(fmaxf(o[8],  0.f), fmaxf(o[9],  0.f));
                wr[9]  = pkrtz(fmaxf(o[10], 0.f), fmaxf(o[11], 0.f));
                wr[12] = pkrtz(fmaxf(o[12], 0.f), fmaxf(o[13], 0.f));
                wr[13] = pkrtz(fmaxf(o[14], 0.f), fmaxf(o[15], 0.f));
            }
        }
        __syncthreads();

        // ---- stage B: 20 cin MFMAs, K=320 total ----
        f32x16 acc = {};
        #pragma unroll
        for (int cin = 0; cin < NC; ++cin) {
            const uint4 bw = w2f[cin * 64 + lane];       // L1-resident
            const unsigned short* pA = &s_o1[cin * PS1 + offA];
            uint4 aw;
            aw.x = *(const unsigned int*)(pA);
            aw.y = *(const unsigned int*)(pA + 2);
            aw.z = *(const unsigned int*)(pA + SO1);
            aw.w = *(const unsigned int*)(pA + SO1 + 2);
            acc = __builtin_amdgcn_mfma_f32_32x32x16_f16(
                      __builtin_bit_cast(h8, aw),
                      __builtin_bit_cast(h8, bw), acc, 0, 0, 0);
        }

        // ---- epilogue: acc -> s_o2 (f16; zeros at halo/out-of-image) ----
        if (l31 < NC) {
            #pragma unroll
            for (int p = 0; p < 16; ++p) {
                const int mr  = (p & 3) + 8 * (p >> 2) + 4 * kh;
                const int qq  = 32 * wv + mr;
                if (qq < 98) {
                    const int li2 = (qq * 2341) >> 15;
                    const int jl2 = qq - li2 * 14;
                    const int ilt = 7 * h + li2;
                    const int oi  = y0 - 1 + ilt, oj = x0 - 1 + jl2;
                    const bool val = (oi >= 0) && (oi < 128) &&
                                     (oj >= 0) && (oj < 128);
                    s_o2[l31 * PS2 + ilt * SO2 + jl2] =
                        val ? f2h(fmaxf(acc[p], 0.f)) : (unsigned short)0;
                }
            }
        }
        __syncthreads();
    }

    // ---- stage C: 3x3 conv over s_o2 -> out ----
    if (tid < TS * TS) {
        const int oy = tid / TS;
        const int ox = tid - oy * TS;
        const int e  = ox & ~1;
        const int par = ox & 1;
        float accc = 0.f;
        for (int c = 0; c < NC; ++c) {
            #pragma unroll
            for (int di = 0; di < 3; ++di) {
                const unsigned int* row =
                    (const unsigned int*)&s_o2[c * PS2 + (oy + di) * SO2 + e];
                const unsigned int d0 = row[0];
                const unsigned int d1 = row[1];
                const unsigned int mm = __builtin_amdgcn_perm(d1, d0, 0x05040302u);
                const unsigned int u0 = par ? mm : d0;
                const unsigned int wa = w3p[c * 9 + di * 3 + 0];
                const unsigned int wb = w3p[c * 9 + di * 3 + 1];
                const unsigned int wc = w3p[c * 9 + di * 3 + 2];
                accc = dot2(u0, wa, accc);
                accc = dot2(d1, par ? wc : wb, accc);
            }
        }
        const int gy = y0 + oy, gx = x0 + ox;
        if (gy < 128 && gx < 128)   // tiles cover 132>128 px: guard edge tiles
            out[(size_t)img * (128 * 128) + gy * 128 + gx] = fmaxf(accc, 0.f);
    }
}

extern "C" void kernel_launch(void* const* d_in, const int* in_sizes, int n_in,
                              void* d_out, int out_size, void* d_ws, size_t ws_size,
                              hipStream_t stream) {
    const float* x  = (const float*)d_in[0];
    const float* w1 = (const float*)d_in[1];
    const float* w2 = (const float*)d_in[2];
    const float* w3 = (const float*)d_in[3];
    unsigned int* wp = (unsigned int*)d_ws;
    float* out = (float*)d_out;
    pack_weights<<<dim3((WP_N + 255) / 256), dim3(256), 0, stream>>>(w1, w2, w3, wp);
    ds_fused<<<dim3(48 * 121), dim3(256), 0, stream>>>(x, wp, out);
}

// Round 9
// 168.293 us; speedup vs baseline: 1.0613x; 1.0613x over previous
//
#include <hip/hip_runtime.h>

// DownSampler fused: x[16,3,512,512] -> out[16,3,128,128] (C folded into N: 48 imgs)
//  S1: reflect-pad1 + 4x4/s2 conv (1->20) + relu   (MFMA 32x32x16 f16)
//  S2: reflect-pad1 + 4x4/s2 conv (20->20) + relu  (MFMA 32x32x16 f16)
//  S3: 3x3 zero-pad1 conv (20->1) + relu           (VALU dot2 f16)
//
// Round 9 = round 8's all-MFMA structure + round 7's memory behavior:
//  - x-taps for each half loaded UPFRONT into registers (4 chunks x 2 rows x 4
//    contiguous floats -> compiler merges to wide loads; full ILP, one wait),
//    h=1 taps issued before the first barrier so they retire under stage B h=0.
//  - interior tiles (ty,tx in [1,9]; 81/121 blocks) skip all epilogue validity
//    math (all 14x14 o2 positions provably valid).
//  - same LDS layout / barriers (4) / garbage-safe OOR slot policy as R8.

#define NC 20
#define TS 12     // output tile
#define AR 16     // o1pad rows per half
#define SO1 48    // s_o1 row stride (shorts)
#define PS1 770   // s_o1 channel plane stride (shorts) = 16*48+2
#define SO2 16    // s_o2 row stride (shorts)
#define PS2 226   // s_o2 channel plane stride (shorts) = 14*16+2

// d_ws layout (u32):
//   [0,256)       w1f[lane][4]   f16 MFMA B-frags: B[k=(l>>5)*8+j][ch=l&31] = w1[ch][k]
//   [256,5376)    w2f[cin][lane][4]  f16 B-frags: B[k][cout] = w2[cout][cin][k]
//   [5376,5556)   w3p[c][di][which]  f16 pairs; 0=(w0,w1) 1=(w2,0) 2=(0,w2)
#define W2F_OFF 256
#define W3_OFF  5376
#define WP_N    5556

typedef _Float16 h2  __attribute__((ext_vector_type(2)));
typedef __fp16   hq2 __attribute__((ext_vector_type(2)));   // cvt_pkrtz ret type
typedef _Float16 h8  __attribute__((ext_vector_type(8)));
typedef float    f32x16 __attribute__((ext_vector_type(16)));

__device__ __forceinline__ float dot2(unsigned int a, unsigned int b, float c) {
    return __builtin_amdgcn_fdot2(__builtin_bit_cast(h2, a),
                                  __builtin_bit_cast(h2, b), c, false);
}
__device__ __forceinline__ unsigned int packh(float a, float b) {
    _Float16 ha = (_Float16)a, hb = (_Float16)b;
    return (unsigned int)__builtin_bit_cast(unsigned short, ha) |
           ((unsigned int)__builtin_bit_cast(unsigned short, hb) << 16);
}
__device__ __forceinline__ unsigned int pkrtz(float a, float b) {
    hq2 r = __builtin_amdgcn_cvt_pkrtz(a, b);
    return __builtin_bit_cast(unsigned int, r);
}
__device__ __forceinline__ unsigned short f2h(float a) {
    _Float16 h = (_Float16)a;
    return __builtin_bit_cast(unsigned short, h);
}
__device__ __forceinline__ int refl256(int q) {          // reflect into [0,256)
    q = (q < 0) ? -q : q; return (q > 255) ? 510 - q : q;
}
__device__ __forceinline__ int refl512(int q) {          // reflect into [0,512)
    q = (q < 0) ? -q : q; return (q > 511) ? 1022 - q : q;
}

__global__ __launch_bounds__(256) void pack_weights(
    const float* __restrict__ w1, const float* __restrict__ w2,
    const float* __restrict__ w3, unsigned int* __restrict__ wp)
{
    const int i = blockIdx.x * 256 + threadIdx.x;
    if (i >= WP_N) return;
    if (i < W2F_OFF) {                      // w1f
        const int lane = i >> 2, jp = i & 3;
        const int ch = lane & 31, k0 = (lane >> 5) * 8 + 2 * jp;
        wp[i] = (ch < NC) ? packh(w1[ch * 16 + k0], w1[ch * 16 + k0 + 1]) : 0u;
    } else if (i < W3_OFF) {                // w2f
        const int t = i - W2F_OFF;
        const int cin = t >> 8, r = t & 255;
        const int lane = r >> 2, jp = r & 3;
        const int cout = lane & 31, k0 = (lane >> 5) * 8 + 2 * jp;
        wp[i] = (cout < NC) ? packh(w2[(cout * NC + cin) * 16 + k0],
                                    w2[(cout * NC + cin) * 16 + k0 + 1]) : 0u;
    } else {                                // w3p
        const int t = i - W3_OFF;
        const int c = t / 9;
        const int r = t - c * 9;
        const int di = r / 3, wh = r - di * 3;
        const float* row = w3 + c * 9 + di * 3;
        float a, b;
        if (wh == 0)      { a = row[0]; b = row[1]; }
        else if (wh == 1) { a = row[2]; b = 0.f;    }
        else              { a = 0.f;    b = row[2]; }
        wp[i] = packh(a, b);
    }
}

// Load + pack one half's x-taps for this thread's 4 stage-A chunks.
__device__ __forceinline__ void load_taps(
    const float* __restrict__ xi, int t0, int h, int wv, int kh,
    bool rowEdge, bool colEdge, int vb, int v0, int v1, int v2, int v3,
    unsigned int xw[4][4])
{
    #pragma unroll
    for (int i = 0; i < 4; ++i) {
        const int c = wv + 4 * i;
        const int t = t0 + 14 * h + c;     // o1pad row (garbage-safe OOR)
        int rlo, rhi;
        if (!rowEdge) {
            rlo = 2 * t - 3 + 2 * kh;      // interior-proven in range
            rhi = rlo + 1;
        } else {
            const int mr = refl256(t - 1);
            const int rb = 2 * mr - 1 + 2 * kh;
            rlo = refl512(rb);
            rhi = refl512(rb + 1);
        }
        const float* __restrict__ plo = xi + rlo * 512;
        const float* __restrict__ phi = xi + rhi * 512;
        float f0, f1, f2, f3, f4, f5, f6, f7;
        if (!colEdge) {
            f0 = plo[vb]; f1 = plo[vb + 1]; f2 = plo[vb + 2]; f3 = plo[vb + 3];
            f4 = phi[vb]; f5 = phi[vb + 1]; f6 = phi[vb + 2]; f7 = phi[vb + 3];
        } else {
            f0 = plo[v0]; f1 = plo[v1]; f2 = plo[v2]; f3 = plo[v3];
            f4 = phi[v0]; f5 = phi[v1]; f6 = phi[v2]; f7 = phi[v3];
        }
        xw[i][0] = pkrtz(f0, f1); xw[i][1] = pkrtz(f2, f3);
        xw[i][2] = pkrtz(f4, f5); xw[i][3] = pkrtz(f6, f7);
    }
}

__global__ __launch_bounds__(256, 4) void ds_fused(
    const float* __restrict__ x,              // [48][512][512]
    const unsigned int* __restrict__ wp,      // packed weights (d_ws)
    float* __restrict__ out)                  // [48][128][128]
{
    __shared__ __attribute__((aligned(16))) unsigned short s_o1[NC * PS1]; // 30,800 B
    __shared__ __attribute__((aligned(16))) unsigned short s_o2[NC * PS2]; //  9,040 B

    const int bid  = blockIdx.x;
    const int img  = bid / 121;
    const int t121 = bid - img * 121;
    const int ty   = t121 / 11;
    const int tx   = t121 - ty * 11;
    const int y0   = ty * TS;
    const int x0   = tx * TS;
    const int tid  = threadIdx.x;
    const int lane = tid & 63;
    const int wv   = tid >> 6;
    const int l31  = lane & 31;
    const int kh   = lane >> 5;

    const float* __restrict__ xi = x + (size_t)img * (512 * 512);
    const uint4* __restrict__ w1f = (const uint4*)wp;
    const uint4* __restrict__ w2f = (const uint4*)(wp + W2F_OFF);
    const unsigned int* __restrict__ w3p = wp + W3_OFF;

    const int t0 = 2 * y0 - 2;            // o1pad row base of tile
    const int s0 = 2 * x0 - 2;            // o1pad col base

    // ---- stage-A per-lane column data (chunk covers cols b = l31) ----
    const int sA = s0 + l31;              // o1pad col (garbage-safe overflow)
    const bool rowEdge = (ty == 0) || (ty == 10);
    const bool colEdge = (tx == 0) || (tx == 10);
    const bool interior = !rowEdge && !colEdge;
    const int vb = 2 * sA - 3;            // interior fast path taps vb..vb+3
    int v0 = 0, v1 = 0, v2 = 0, v3 = 0;
    if (colEdge) {
        const int n2 = refl256(sA - 1);
        const int vbb = 2 * n2 - 1;
        v0 = refl512(vbb);     v1 = refl512(vbb + 1);
        v2 = refl512(vbb + 2); v3 = refl512(vbb + 3);
    }
    const h8 w1frag = __builtin_bit_cast(h8, w1f[lane]);

    // ---- stage-B per-lane position (chunk = wv), h-independent ----
    const int q  = 32 * wv + l31;         // 0..127; valid < 98 (7x14 per half)
    const int qc = (q < 98) ? q : 0;      // clamp invalid lanes to a safe addr
    const int li = (qc * 2341) >> 15;     // /14 for q<128
    const int jl = qc - li * 14;
    const int offA = (2 * li + 2 * kh) * SO1 + 2 * jl;   // shorts, within plane

    // ================= h = 0 =================
    unsigned int xw0[4][4];
    load_taps(xi, t0, 0, wv, kh, rowEdge, colEdge, vb, v0, v1, v2, v3, xw0);

    // stage A (h=0): 4 chunks -> s_o1
    #pragma unroll
    for (int i = 0; i < 4; ++i) {
        const int c = wv + 4 * i;
        uint4 aw; aw.x = xw0[i][0]; aw.y = xw0[i][1];
                  aw.z = xw0[i][2]; aw.w = xw0[i][3];
        f32x16 o = {};
        o = __builtin_amdgcn_mfma_f32_32x32x16_f16(
                __builtin_bit_cast(h8, aw), w1frag, o, 0, 0, 0);
        if (l31 < NC) {
            unsigned int* wr = (unsigned int*)&s_o1[l31 * PS1 + c * SO1 + 4 * kh];
            wr[0]  = pkrtz(fmaxf(o[0],  0.f), fmaxf(o[1],  0.f));
            wr[1]  = pkrtz(fmaxf(o[2],  0.f), fmaxf(o[3],  0.f));
            wr[4]  = pkrtz(fmaxf(o[4],  0.f), fmaxf(o[5],  0.f));
            wr[5]  = pkrtz(fmaxf(o[6],  0.f), fmaxf(o[7],  0.f));
            wr[8]  = pkrtz(fmaxf(o[8],  0.f), fmaxf(o[9],  0.f));
            wr[9]  = pkrtz(fmaxf(o[10], 0.f), fmaxf(o[11], 0.f));
            wr[12] = pkrtz(fmaxf(o[12], 0.f), fmaxf(o[13], 0.f));
            wr[13] = pkrtz(fmaxf(o[14], 0.f), fmaxf(o[15], 0.f));
        }
    }

    // prefetch h=1 taps now; they retire during stage B (h=0)
    unsigned int xw1[4][4];
    load_taps(xi, t0, 1, wv, kh, rowEdge, colEdge, vb, v0, v1, v2, v3, xw1);

    #pragma unroll
    for (int h = 0; h < 2; ++h) {
        if (h == 1) {
            __syncthreads();              // B(h=0) reads done
            // stage A (h=1) from prefetched registers
            #pragma unroll
            for (int i = 0; i < 4; ++i) {
                const int c = wv + 4 * i;
                uint4 aw; aw.x = xw1[i][0]; aw.y = xw1[i][1];
                          aw.z = xw1[i][2]; aw.w = xw1[i][3];
                f32x16 o = {};
                o = __builtin_amdgcn_mfma_f32_32x32x16_f16(
                        __builtin_bit_cast(h8, aw), w1frag, o, 0, 0, 0);
                if (l31 < NC) {
                    unsigned int* wr =
                        (unsigned int*)&s_o1[l31 * PS1 + c * SO1 + 4 * kh];
                    wr[0]  = pkrtz(fmaxf(o[0],  0.f), fmaxf(o[1],  0.f));
                    wr[1]  = pkrtz(fmaxf(o[2],  0.f), fmaxf(o[3],  0.f));
                    wr[4]  = pkrtz(fmaxf(o[4],  0.f), fmaxf(o[5],  0.f));
                    wr[5]  = pkrtz(fmaxf(o[6],  0.f), fmaxf(o[7],  0.f));
                    wr[8]  = pkrtz(fmaxf(o[8],  0.f), fmaxf(o[9],  0.f));
                    wr[9]  = pkrtz(fmaxf(o[10], 0.f), fmaxf(o[11], 0.f));
                    wr[12] = pkrtz(fmaxf(o[12], 0.f), fmaxf(o[13], 0.f));
                    wr[13] = pkrtz(fmaxf(o[14], 0.f), fmaxf(o[15], 0.f));
                }
            }
        }
        __syncthreads();                  // A(h) writes visible

        // ---- stage B: 20 cin MFMAs, K=320 total ----
        f32x16 acc = {};
        #pragma unroll
        for (int cin = 0; cin < NC; ++cin) {
            const uint4 bw = w2f[cin * 64 + lane];       // L1-resident
            const unsigned short* pA = &s_o1[cin * PS1 + offA];
            uint4 aw;
            aw.x = *(const unsigned int*)(pA);
            aw.y = *(const unsigned int*)(pA + 2);
            aw.z = *(const unsigned int*)(pA + SO1);
            aw.w = *(const unsigned int*)(pA + SO1 + 2);
            acc = __builtin_amdgcn_mfma_f32_32x32x16_f16(
                      __builtin_bit_cast(h8, aw),
                      __builtin_bit_cast(h8, bw), acc, 0, 0, 0);
        }

        // ---- epilogue: acc -> s_o2 (interior fast path skips validity) ----
        if (l31 < NC) {
            #pragma unroll
            for (int p = 0; p < 16; ++p) {
                const int mr = (p & 3) + 8 * (p >> 2) + 4 * kh;
                const int qq = 32 * wv + mr;
                if (qq < 98) {
                    const int li2 = (qq * 2341) >> 15;
                    const int jl2 = qq - li2 * 14;
                    const int ilt = 7 * h + li2;
                    if (interior) {
                        s_o2[l31 * PS2 + ilt * SO2 + jl2] = f2h(fmaxf(acc[p], 0.f));
                    } else {
                        const int oi = y0 - 1 + ilt, oj = x0 - 1 + jl2;
                        const bool val = (oi >= 0) && (oi < 128) &&
                                         (oj >= 0) && (oj < 128);
                        s_o2[l31 * PS2 + ilt * SO2 + jl2] =
                            val ? f2h(fmaxf(acc[p], 0.f)) : (unsigned short)0;
                    }
                }
            }
        }
    }
    __syncthreads();

    // ---- stage C: 3x3 conv over s_o2 -> out ----
    if (tid < TS * TS) {
        const int oy = tid / TS;
        const int ox = tid - oy * TS;
        const int e  = ox & ~1;
        const int par = ox & 1;
        float accc = 0.f;
        for (int c = 0; c < NC; ++c) {
            #pragma unroll
            for (int di = 0; di < 3; ++di) {
                const unsigned int* row =
                    (const unsigned int*)&s_o2[c * PS2 + (oy + di) * SO2 + e];
                const unsigned int d0 = row[0];
                const unsigned int d1 = row[1];
                const unsigned int mm = __builtin_amdgcn_perm(d1, d0, 0x05040302u);
                const unsigned int u0 = par ? mm : d0;
                const unsigned int wa = w3p[c * 9 + di * 3 + 0];
                const unsigned int wb = w3p[c * 9 + di * 3 + 1];
                const unsigned int wc = w3p[c * 9 + di * 3 + 2];
                accc = dot2(u0, wa, accc);
                accc = dot2(d1, par ? wc : wb, accc);
            }
        }
        const int gy = y0 + oy, gx = x0 + ox;
        if (gy < 128 && gx < 128)   // tiles cover 132>128 px: guard edge tiles
            out[(size_t)img * (128 * 128) + gy * 128 + gx] = fmaxf(accc, 0.f);
    }
}

extern "C" void kernel_launch(void* const* d_in, const int* in_sizes, int n_in,
                              void* d_out, int out_size, void* d_ws, size_t ws_size,
                              hipStream_t stream) {
    const float* x  = (const float*)d_in[0];
    const float* w1 = (const float*)d_in[1];
    const float* w2 = (const float*)d_in[2];
    const float* w3 = (const float*)d_in[3];
    unsigned int* wp = (unsigned int*)d_ws;
    float* out = (float*)d_out;
    pack_weights<<<dim3((WP_N + 255) / 256), dim3(256), 0, stream>>>(w1, w2, w3, wp);
    ds_fused<<<dim3(48 * 121), dim3(256), 0, stream>>>(x, wp, out);
}